// Round 5
// baseline (266.883 us; speedup 1.0000x reference)
//
#include <hip/hip_runtime.h>
#include <hip/hip_bf16.h>
#include <stdint.h>

// QuantizedLinear: out[16,11008] = x[16,4096] @ ((W - zp)*scale)^T
// HARNESS NOTE: W arrives as a 180 MB int32 buffer. Roofline = 180 MB /
// 6.3 TB/s ~ 29 us; harness fillBuffer resets (~210 us/iter, 86% peak) are
// untouchable context.
//
// History: R3 (contiguous 1KB staging) 47->40 us our-portion. R4 (counted
// vmcnt, no barrier drain) NULL -> chunk cadence 5500 cy >> 900 cy HBM
// latency, so latency structure is irrelevant; qgemm is BW-limited at
// ~5.0 TB/s vs the fills' 6.86 TB/s.
//
// R5: make the read stream FILL-SHAPED. A block's 16 output rows are one
// contiguous 256 KB region of W, so stage the ENTIRE tile with a single
// linear sweep (64 KB packed int8 in LDS), then compute barrier-free.
// 688 long sequential streams chip-wide instead of 11008 x 16 revisits.
// LDS 68.4 KB -> 2 blocks/CU, 8 waves/CU (32 KB in flight >> 10 KB
// Little's-law requirement).

#define M_TOK 16
#define K_DIM 4096
#define N_OUT 11008

typedef int v4i __attribute__((ext_vector_type(4)));

// ---------------- Kernel 1: per-token quantization of x ----------------
// ws layout: xh[16*4096] | xl[16*4096] | s1[16] | sumx[16]
__global__ __launch_bounds__(256) void quant_x_kernel(
    const float* __restrict__ x, int8_t* __restrict__ xh,
    int8_t* __restrict__ xl, float* __restrict__ s1_out,
    float* __restrict__ sumx_out) {
  const int t = blockIdx.x;      // token
  const int tid = threadIdx.x;   // 256 threads, 16 consecutive elems each
  const float4* xv = (const float4*)(x + (long)t * K_DIM) + tid * 4;

  float vals[16];
  float m = 0.0f, s = 0.0f;
#pragma unroll
  for (int j = 0; j < 4; ++j) {
    float4 f = xv[j];
    vals[j * 4 + 0] = f.x; vals[j * 4 + 1] = f.y;
    vals[j * 4 + 2] = f.z; vals[j * 4 + 3] = f.w;
    m = fmaxf(m, fmaxf(fmaxf(fabsf(f.x), fabsf(f.y)),
                       fmaxf(fabsf(f.z), fabsf(f.w))));
    s += f.x + f.y + f.z + f.w;
  }
#pragma unroll
  for (int off = 32; off > 0; off >>= 1) {
    m = fmaxf(m, __shfl_xor(m, off));
    s += __shfl_xor(s, off);
  }
  __shared__ float lm[4], ls[4];
  const int w = tid >> 6;
  if ((tid & 63) == 0) { lm[w] = m; ls[w] = s; }
  __syncthreads();
  m = fmaxf(fmaxf(lm[0], lm[1]), fmaxf(lm[2], lm[3]));
  s = ls[0] + ls[1] + ls[2] + ls[3];

  const float s1 = (m > 0.0f) ? (m * (1.0f / 127.0f)) : 1.0f;
  const float inv = 1.0f / s1;
  if (tid == 0) { s1_out[t] = s1; sumx_out[t] = s; }

  int hq[16], lq[16];
#pragma unroll
  for (int j = 0; j < 16; ++j) {
    float xf = vals[j];
    float h = rintf(xf * inv);
    h = fminf(fmaxf(h, -127.0f), 127.0f);
    float resid = xf - h * s1;
    float l = rintf(resid * inv * 256.0f);
    l = fminf(fmaxf(l, -128.0f), 127.0f);
    hq[j] = (int)h;
    lq[j] = (int)l;
  }
  int4 hv, lv;
  int* hp = (int*)&hv;
  int* lp = (int*)&lv;
#pragma unroll
  for (int d = 0; d < 4; ++d) {
    uint32_t hw = 0, lw = 0;
#pragma unroll
    for (int j = 0; j < 4; ++j) {
      hw |= (uint32_t)(hq[d * 4 + j] & 0xff) << (8 * j);
      lw |= (uint32_t)(lq[d * 4 + j] & 0xff) << (8 * j);
    }
    hp[d] = (int)hw;
    lp[d] = (int)lw;
  }
  ((int4*)xh)[(long)t * 256 + tid] = hv;
  ((int4*)xl)[(long)t * 256 + tid] = lv;
}

// ---------------- Kernel 2: stage-all-K linear-sweep i8 MFMA GEMM ---------
// Grid = 688 blocks x 256 thr (4 waves). Block owns 16 output rows = one
// contiguous 256 KB slab of W.
// Phase 1: all 4 waves sweep the slab in LINEAR memory order (instruction i
//   covers 4 KB contiguous), pack int32->int8, write XOR-swizzled LDS.
// Phase 2 (after ONE barrier): wave w computes K quarter [w*1024,+1024) --
//   16 x { ds_read_b128 B-frag + hi/lo MFMA }, no barriers.
// Epilogue: 4-way K reduction in LDS, direct store.
__global__ __launch_bounds__(256) void qgemm_kernel(
    const int* __restrict__ W, const int8_t* __restrict__ xh,
    const int8_t* __restrict__ xl, const float* __restrict__ s1,
    const float* __restrict__ sumx, const float* __restrict__ scale_p,
    const int* __restrict__ zp_p, float* __restrict__ out) {
  const int tid = threadIdx.x;
  const int lane = tid & 63;
  const int w = tid >> 6;          // wave id = K quarter
  const int obase = blockIdx.x * 16;
  const int n = lane & 15;         // output-row (B col) / token (A row)
  const int g = lane >> 4;         // k sub-group within 64-k window

  __shared__ uint32_t wbuf[16 * 1024];   // packed int8 tile, swizzled
  __shared__ float red[4][16 * 17];

  // ---- Phase 1: linear slab stage ----
  // slab = block's 16 rows, contiguous: 16*4096 int32 = 16384 v4i.
  // Iteration i: 256 threads read v4i at [i*256 + tid] -> 4 KB contiguous.
  const v4i* slab = (const v4i*)(W + (long)obase * K_DIM);
#pragma unroll
  for (int b = 0; b < 16; ++b) {
    v4i q0 = slab[(b * 4 + 0) * 256 + tid];
    v4i q1 = slab[(b * 4 + 1) * 256 + tid];
    v4i q2 = slab[(b * 4 + 2) * 256 + tid];
    v4i q3 = slab[(b * 4 + 3) * 256 + tid];
#pragma unroll
    for (int u = 0; u < 4; ++u) {
      v4i q = (u == 0) ? q0 : (u == 1) ? q1 : (u == 2) ? q2 : q3;
      const int idx = (b * 4 + u) * 256 + tid;   // v4i index in slab
      const int row = idx >> 10;                 // 1024 v4i per weight row
      const int k4 = idx & 1023;                 // packed-dword idx in row
      uint32_t p = ((uint32_t)q.x & 0xffu) |
                   (((uint32_t)q.y & 0xffu) << 8) |
                   (((uint32_t)q.z & 0xffu) << 16) |
                   (((uint32_t)q.w & 0xffu) << 24);
      // Swizzle at b128-slot granularity: slot j=k4>>2 XOR'd with row&7 so
      // phase-2 reads (16 lanes, same slot, rows 0..15) spread all banks.
      const int wr = (row << 10) | (((k4 >> 2) ^ (row & 7)) << 2) | (k4 & 3);
      wbuf[wr] = p;
    }
  }
  __syncthreads();

  // ---- Phase 2: barrier-free compute ----
  // A fragments (L2-resident x planes), v4i index = n*256 + w*64 + it*4 + g.
  const v4i* Ah = (const v4i*)xh + n * 256 + w * 64 + g;
  const v4i* Al = (const v4i*)xl + n * 256 + w * 64 + g;
  v4i accH = {0, 0, 0, 0};
  v4i accL = {0, 0, 0, 0};
#pragma unroll
  for (int it = 0; it < 16; ++it) {
    const int j = w * 64 + it * 4 + g;   // b128 slot within row n
    const v4i b = *(const v4i*)&wbuf[(n << 10) | ((j ^ (n & 7)) << 2)];
    accH = __builtin_amdgcn_mfma_i32_16x16x64_i8(Ah[it * 4], b, accH, 0, 0, 0);
    accL = __builtin_amdgcn_mfma_i32_16x16x64_i8(Al[it * 4], b, accL, 0, 0, 0);
  }

  // C layout (16x16): col = lane&15 (=o), row = (lane>>4)*4 + reg (=token)
#pragma unroll
  for (int r = 0; r < 4; ++r) {
    float f = (float)accH[r] + (float)accL[r] * (1.0f / 256.0f);
    const int t = g * 4 + r;
    red[w][t * 17 + n] = f;
  }
  __syncthreads();

  const int t = tid >> 4;
  const int col = tid & 15;
  const float sum = red[0][t * 17 + col] + red[1][t * 17 + col] +
                    red[2][t * 17 + col] + red[3][t * 17 + col];
  const float sc = scale_p[0];
  const float zp = (float)zp_p[0];
  const float o = sc * (s1[t] * sum) - sc * zp * sumx[t];
  out[(long)t * N_OUT + obase + col] = o;
}

extern "C" void kernel_launch(void* const* d_in, const int* in_sizes, int n_in,
                              void* d_out, int out_size, void* d_ws,
                              size_t ws_size, hipStream_t stream) {
  const float* x = (const float*)d_in[0];
  const int* Wq = (const int*)d_in[1];          // int inputs come as int32
  const float* scale_p = (const float*)d_in[2];
  const int* zp_p = (const int*)d_in[3];
  float* out = (float*)d_out;

  int8_t* xh = (int8_t*)d_ws;
  int8_t* xl = xh + (long)M_TOK * K_DIM;
  float* s1 = (float*)(xl + (long)M_TOK * K_DIM);
  float* sumx = s1 + M_TOK;

  quant_x_kernel<<<M_TOK, 256, 0, stream>>>(x, xh, xl, s1, sumx);
  qgemm_kernel<<<N_OUT / 16, 256, 0, stream>>>(Wq, xh, xl, s1, sumx, scale_p,
                                               zp_p, out);
}

// Round 6
// 252.804 us; speedup vs baseline: 1.0557x; 1.0557x over previous
//
#include <hip/hip_runtime.h>
#include <hip/hip_bf16.h>
#include <stdint.h>

// QuantizedLinear: out[16,11008] = x[16,4096] @ ((W - zp)*scale)^T
// HARNESS NOTE: W arrives as a 180 MB int32 buffer. Roofline = 180 MB /
// 6.3 TB/s ~ 29 us; harness fillBuffer resets (~210 us/iter, 86% peak) are
// untouchable context. qgemm read BW to date: R0 4.3 -> R3 5.0 TB/s.
//
// Ladder: R3 (+7us): 256B->1KB row-visit granule. R4 null: sync/latency
// structure irrelevant (chunk cadence 5500cy >> 900cy HBM). R5 regression:
// stage-all-K dropped to 2 blocks/CU -> 176-block batch tail + probable
// VGPR spill from 64-load unroll; did NOT test granule cleanly.
//
// R6: middle of the granule curve at FULL occupancy. Chunk K=1024 (4
// chunks): wave stages its 4 rows as 4 consecutive 1KB instructions per
// row (4KB sequential run per row-visit). LDS 37.1KB (2x16KB dbuf + red)
// -> grid-limited 2.69 blocks/CU, no batch tail. 1-chunk reg pipeline
// (~120 VGPR, no spill). Barriers 16 -> 4, lgkm-only. Single-variable A/B
// vs R3 on stream granule.

#define M_TOK 16
#define K_DIM 4096
#define N_OUT 11008

typedef int v4i __attribute__((ext_vector_type(4)));

// ---------------- Kernel 1: per-token quantization of x ----------------
// ws layout: xh[16*4096] | xl[16*4096] | s1[16] | sumx[16]
__global__ __launch_bounds__(256) void quant_x_kernel(
    const float* __restrict__ x, int8_t* __restrict__ xh,
    int8_t* __restrict__ xl, float* __restrict__ s1_out,
    float* __restrict__ sumx_out) {
  const int t = blockIdx.x;      // token
  const int tid = threadIdx.x;   // 256 threads, 16 consecutive elems each
  const float4* xv = (const float4*)(x + (long)t * K_DIM) + tid * 4;

  float vals[16];
  float m = 0.0f, s = 0.0f;
#pragma unroll
  for (int j = 0; j < 4; ++j) {
    float4 f = xv[j];
    vals[j * 4 + 0] = f.x; vals[j * 4 + 1] = f.y;
    vals[j * 4 + 2] = f.z; vals[j * 4 + 3] = f.w;
    m = fmaxf(m, fmaxf(fmaxf(fabsf(f.x), fabsf(f.y)),
                       fmaxf(fabsf(f.z), fabsf(f.w))));
    s += f.x + f.y + f.z + f.w;
  }
#pragma unroll
  for (int off = 32; off > 0; off >>= 1) {
    m = fmaxf(m, __shfl_xor(m, off));
    s += __shfl_xor(s, off);
  }
  __shared__ float lm[4], ls[4];
  const int w = tid >> 6;
  if ((tid & 63) == 0) { lm[w] = m; ls[w] = s; }
  __syncthreads();
  m = fmaxf(fmaxf(lm[0], lm[1]), fmaxf(lm[2], lm[3]));
  s = ls[0] + ls[1] + ls[2] + ls[3];

  const float s1 = (m > 0.0f) ? (m * (1.0f / 127.0f)) : 1.0f;
  const float inv = 1.0f / s1;
  if (tid == 0) { s1_out[t] = s1; sumx_out[t] = s; }

  int hq[16], lq[16];
#pragma unroll
  for (int j = 0; j < 16; ++j) {
    float xf = vals[j];
    float h = rintf(xf * inv);
    h = fminf(fmaxf(h, -127.0f), 127.0f);
    float resid = xf - h * s1;
    float l = rintf(resid * inv * 256.0f);
    l = fminf(fmaxf(l, -128.0f), 127.0f);
    hq[j] = (int)h;
    lq[j] = (int)l;
  }
  int4 hv, lv;
  int* hp = (int*)&hv;
  int* lp = (int*)&lv;
#pragma unroll
  for (int d = 0; d < 4; ++d) {
    uint32_t hw = 0, lw = 0;
#pragma unroll
    for (int j = 0; j < 4; ++j) {
      hw |= (uint32_t)(hq[d * 4 + j] & 0xff) << (8 * j);
      lw |= (uint32_t)(lq[d * 4 + j] & 0xff) << (8 * j);
    }
    hp[d] = (int)hw;
    lp[d] = (int)lw;
  }
  ((int4*)xh)[(long)t * 256 + tid] = hv;
  ((int4*)xl)[(long)t * 256 + tid] = lv;
}

// ---------------- Kernel 2: LDS-staged i8 MFMA GEMM, 4KB-granule chunks ---
// Grid = 688 blocks x 256 thr (4 waves). Block owns 16 output rows, full K.
// Chunk = 1024 k. Per chunk: wave w stages rows 4w..4w+3, 4 KB sequential
// per row (4 x 1KB instructions), packs int32->int8, writes XOR-swizzled
// LDS. Compute: per chunk each wave does 4 x {ds_read_b128 + hi/lo MFMA}
// on its K-quarter. 4 chunks, 2x16KB LDS dbuf, lgkm-only barriers.
__global__ __launch_bounds__(256) void qgemm_kernel(
    const int* __restrict__ W, const int8_t* __restrict__ xh,
    const int8_t* __restrict__ xl, const float* __restrict__ s1,
    const float* __restrict__ sumx, const float* __restrict__ scale_p,
    const int* __restrict__ zp_p, float* __restrict__ out) {
  const int tid = threadIdx.x;
  const int lane = tid & 63;
  const int w = tid >> 6;          // wave id
  const int obase = blockIdx.x * 16;
  const int n = lane & 15;         // output-row (B col) / token (A row)
  const int g = lane >> 4;         // k sub-group within 64-k window
  const int r0 = w * 4;            // first staged row for this wave

  __shared__ uint32_t wbuf[2][16 * 256];  // [buf][row*256 + swz dword]
  __shared__ float red[4][16 * 17];

  // Staging pointers: row base + lane*16B. Chunk c sub-load i reads
  // v4i at [c*256 + i*64] (c*4KB + i*1KB per row).
  const v4i* Wr0 = (const v4i*)(W + (long)(obase + r0 + 0) * K_DIM) + lane;
  const v4i* Wr1 = (const v4i*)(W + (long)(obase + r0 + 1) * K_DIM) + lane;
  const v4i* Wr2 = (const v4i*)(W + (long)(obase + r0 + 2) * K_DIM) + lane;
  const v4i* Wr3 = (const v4i*)(W + (long)(obase + r0 + 3) * K_DIM) + lane;

  // LDS write index (dwords): row r, sub i, lane -> packed dword index
  // p = i*64 + lane; swizzle slot (p>>2) with row&7:
  // idx = r*256 + i*64 + (((lane>>2) ^ (r&7))<<2) + (lane&3).
  int wbase[4];
#pragma unroll
  for (int r = 0; r < 4; ++r) {
    const int row = r0 + r;
    wbase[r] = row * 256 + ((((lane >> 2) ^ (row & 7)) << 2) | (lane & 3));
  }

  // A fragments (L2-resident x planes): v4i idx = n*256 + c*64 + w*16 +
  // it*4 + g for chunk c, step it.
  const v4i* Ah = (const v4i*)xh + n * 256 + w * 16 + g;
  const v4i* Al = (const v4i*)xl + n * 256 + w * 16 + g;

  v4i wr_[4][4];   // [sub i][row r]
#define STAGE_LOAD(c)                                                        \
  {                                                                          \
    _Pragma("unroll") for (int i = 0; i < 4; ++i) {                          \
      wr_[i][0] = Wr0[(c) * 256 + i * 64];                                   \
      wr_[i][1] = Wr1[(c) * 256 + i * 64];                                   \
      wr_[i][2] = Wr2[(c) * 256 + i * 64];                                   \
      wr_[i][3] = Wr3[(c) * 256 + i * 64];                                   \
    }                                                                        \
  }
#define STAGE_WRITE(buf)                                                     \
  {                                                                          \
    uint32_t* wb = wbuf[buf];                                                \
    _Pragma("unroll") for (int i = 0; i < 4; ++i) {                          \
      _Pragma("unroll") for (int r = 0; r < 4; ++r) {                        \
        v4i q = wr_[i][r];                                                   \
        uint32_t p = ((uint32_t)q.x & 0xffu) |                               \
                     (((uint32_t)q.y & 0xffu) << 8) |                        \
                     (((uint32_t)q.z & 0xffu) << 16) |                       \
                     (((uint32_t)q.w & 0xffu) << 24);                        \
        wb[wbase[r] + i * 64] = p;                                           \
      }                                                                      \
    }                                                                        \
  }

  // Prologue: stage chunk 0.
  STAGE_LOAD(0);
  STAGE_WRITE(0);
  asm volatile("s_waitcnt lgkmcnt(0)" ::: "memory");
  __builtin_amdgcn_s_barrier();

  v4i accH = {0, 0, 0, 0};
  v4i accL = {0, 0, 0, 0};

#pragma unroll
  for (int c = 0; c < 4; ++c) {
    const int cur = c & 1;
    if (c + 1 < 4) STAGE_LOAD(c + 1);   // in flight during compute
    // Compute chunk c: 4 x (ds_read_b128 + hi/lo MFMA).
#pragma unroll
    for (int it = 0; it < 4; ++it) {
      const int j = w * 16 + it * 4 + g;   // b128 slot within row
      const v4i b =
          *(const v4i*)&wbuf[cur][n * 256 + ((j ^ (n & 7)) << 2)];
      accH = __builtin_amdgcn_mfma_i32_16x16x64_i8(Ah[c * 64 + it * 4], b,
                                                   accH, 0, 0, 0);
      accL = __builtin_amdgcn_mfma_i32_16x16x64_i8(Al[c * 64 + it * 4], b,
                                                   accL, 0, 0, 0);
    }
    if (c + 1 < 4) STAGE_WRITE(cur ^ 1);  // counted vmcnt inside
    asm volatile("s_waitcnt lgkmcnt(0)" ::: "memory");
    __builtin_amdgcn_s_barrier();
  }

  // C layout (16x16): col = lane&15 (=o), row = (lane>>4)*4 + reg (=token)
#pragma unroll
  for (int r = 0; r < 4; ++r) {
    float f = (float)accH[r] + (float)accL[r] * (1.0f / 256.0f);
    const int t = g * 4 + r;
    red[w][t * 17 + n] = f;
  }
  __syncthreads();

  const int t = tid >> 4;
  const int col = tid & 15;
  const float sum = red[0][t * 17 + col] + red[1][t * 17 + col] +
                    red[2][t * 17 + col] + red[3][t * 17 + col];
  const float sc = scale_p[0];
  const float zp = (float)zp_p[0];
  const float o = sc * (s1[t] * sum) - sc * zp * sumx[t];
  out[(long)t * N_OUT + obase + col] = o;
}

extern "C" void kernel_launch(void* const* d_in, const int* in_sizes, int n_in,
                              void* d_out, int out_size, void* d_ws,
                              size_t ws_size, hipStream_t stream) {
  const float* x = (const float*)d_in[0];
  const int* Wq = (const int*)d_in[1];          // int inputs come as int32
  const float* scale_p = (const float*)d_in[2];
  const int* zp_p = (const int*)d_in[3];
  float* out = (float*)d_out;

  int8_t* xh = (int8_t*)d_ws;
  int8_t* xl = xh + (long)M_TOK * K_DIM;
  float* s1 = (float*)(xl + (long)M_TOK * K_DIM);
  float* sumx = s1 + M_TOK;

  quant_x_kernel<<<M_TOK, 256, 0, stream>>>(x, xh, xl, s1, sumx);
  qgemm_kernel<<<N_OUT / 16, 256, 0, stream>>>(Wq, xh, xl, s1, sumx, scale_p,
                                               zp_p, out);
}